// Round 1
// 3268.414 us; speedup vs baseline: 1.8850x; 1.8850x over previous
//
#include <hip/hip_runtime.h>

typedef unsigned short u16;
typedef unsigned int u32;
typedef unsigned long long u64;
using bf16x8 = __attribute__((ext_vector_type(8))) short;
using f32x4  = __attribute__((ext_vector_type(4))) float;

__device__ __forceinline__ u16 f2bf(float f) {
  u32 u = __float_as_uint(f);
  u32 r = (u + 0x7fffu + ((u >> 16) & 1u)) >> 16;
  return (u16)r;
}

__device__ __forceinline__ void gl2lds16(const void* g, void* l) {
  __builtin_amdgcn_global_load_lds((const __attribute__((address_space(1))) u32*)g,
                                   (__attribute__((address_space(3))) u32*)l, 16, 0, 0);
}

// ---------------- embedding gather + bf16 cast: x[t*64+b][:] = emb[inputs[b][t]][:]
__global__ __launch_bounds__(256) void embed_kernel(const int* __restrict__ inp,
                                                    const float* __restrict__ emb,
                                                    u16* __restrict__ x) {
  int m = blockIdx.x;            // = t*64 + b
  int t = m >> 6, b = m & 63;
  int idx = inp[b * 128 + t];
  const float4* src = (const float4*)(emb + (long)idx * 1024);
  float4 v = src[threadIdx.x];
  u32 lo = (u32)f2bf(v.x) | ((u32)f2bf(v.y) << 16);
  u32 hi = (u32)f2bf(v.z) | ((u32)f2bf(v.w) << 16);
  uint2 o; o.x = lo; o.y = hi;
  *(uint2*)(x + (long)m * 1024 + threadIdx.x * 4) = o;
}

// ---------------- cast + transpose: in fp32 [1024][N] -> out bf16 [N][1024]
__global__ __launch_bounds__(256) void castT_kernel(const float* __restrict__ in,
                                                    u16* __restrict__ outp, int N) {
  __shared__ float tile[32][33];
  int n0 = blockIdx.x * 32, k0 = blockIdx.y * 32;
  int tx = threadIdx.x & 31, ty = threadIdx.x >> 5;  // ty 0..7
  #pragma unroll
  for (int i = 0; i < 4; i++)
    tile[ty + 8 * i][tx] = in[(long)(k0 + ty + 8 * i) * N + n0 + tx];
  __syncthreads();
  #pragma unroll
  for (int i = 0; i < 4; i++)
    outp[(long)(n0 + ty + 8 * i) * 1024 + k0 + tx] = f2bf(tile[tx][ty + 8 * i]);
}

// ---------------- m97-style bt-GEMM: C[M][N] = A[M][1024] * Bm[N][1024]^T + bias
__global__ __launch_bounds__(256) void gemm_bt(const u16* __restrict__ A,
                                               const u16* __restrict__ Bm,
                                               const float* __restrict__ bias,
                                               float* __restrict__ C,
                                               int N, int remap) {
  __shared__ u16 As[128 * 64];
  __shared__ u16 Bs[128 * 64];
  const int K = 1024;
  int bn = blockIdx.x, bm = blockIdx.y;
  int tid = threadIdx.x;
  int lane = tid & 63, w = tid >> 6;
  int wy = w >> 1, wx = w & 1;
  int q = lane >> 4, ml = lane & 15;
  int l8 = lane >> 3, s = lane & 7;
  f32x4 acc[4][4] = {};

  const u16* Abase = A + (long)bm * 128 * K;
  const u16* Bbase = Bm + (long)bn * 128 * K;

  for (int kb = 0; kb < 16; kb++) {
    #pragma unroll
    for (int i = 0; i < 4; i++) {
      int row = w * 32 + i * 8 + l8;
      int kc = s ^ (row & 7);
      gl2lds16(Abase + (long)row * K + kb * 64 + kc * 8, &As[(w * 256 + i * 64) * 8]);
    }
    #pragma unroll
    for (int i = 0; i < 4; i++) {
      int row = w * 32 + i * 8 + l8;
      int kc = s ^ (row & 7);
      gl2lds16(Bbase + (long)row * K + kb * 64 + kc * 8, &Bs[(w * 256 + i * 64) * 8]);
    }
    __syncthreads();
    #pragma unroll
    for (int kk = 0; kk < 2; kk++) {
      bf16x8 av[4], bv[4];
      #pragma unroll
      for (int m = 0; m < 4; m++) {
        int r = wy * 64 + m * 16 + ml;
        int p = kk * 4 + q;
        av[m] = *(const bf16x8*)&As[r * 64 + ((p ^ (r & 7)) << 3)];
      }
      #pragma unroll
      for (int n = 0; n < 4; n++) {
        int r = wx * 64 + n * 16 + ml;
        int p = kk * 4 + q;
        bv[n] = *(const bf16x8*)&Bs[r * 64 + ((p ^ (r & 7)) << 3)];
      }
      #pragma unroll
      for (int m = 0; m < 4; m++)
        #pragma unroll
        for (int n = 0; n < 4; n++)
          acc[m][n] = __builtin_amdgcn_mfma_f32_16x16x32_bf16(av[m], bv[n], acc[m][n], 0, 0, 0);
    }
    __syncthreads();
  }
  #pragma unroll
  for (int n = 0; n < 4; n++) {
    int col = bn * 128 + wx * 64 + n * 16 + ml;
    float bvv = bias[col];
    #pragma unroll
    for (int m = 0; m < 4; m++) {
      #pragma unroll
      for (int r = 0; r < 4; r++) {
        int row = bm * 128 + wy * 64 + m * 16 + q * 4 + r;     // row = t*64+b
        int orow = remap ? (((row & 63) << 7) | (row >> 6)) : row;  // -> b*128+t
        C[(long)orow * N + col] = acc[m][n][r] + bvv;
      }
    }
  }
}

// ---------------- persistent cooperative LSTM scan (one layer)
// 4 INDEPENDENT batch-groups (16 batches each) x 64 WGs. WG (g, wi) owns h-cols
// [wi*16, wi*16+16) for group g: 64 U-cols (4 gates x 16) = 128 KB dynamic LDS.
// Cross-WG h exchange is fence-free: writes/reads via relaxed AGENT-scope atomics
// (coherent at LLC, bypass stale per-XCD L1/L2). Barrier = per-group 64-count slot.
__global__ __launch_bounds__(256) void lstm_scan(const float* __restrict__ xz,
                                                 const u16* __restrict__ UT,
                                                 u16* __restrict__ out_seq,
                                                 u16* __restrict__ h_buf, // [4][2][16][1024] bf16
                                                 float* __restrict__ hT,
                                                 float* __restrict__ cT,
                                                 u32* __restrict__ bar) {
  extern __shared__ u16 smem[];
  u16* U_lds = smem;                        // [64][1024] bf16, chunk-swizzled, 128 KB
  float* zpart = (float*)(smem + 65536);    // [4][16][68] f32 partial gate sums, 17408 B

  int bid = blockIdx.x;
  int g  = bid >> 6;                        // group 0..3
  int wi = bid & 63;                        // wg-in-group
  int tid = threadIdx.x;
  int lane = tid & 63, w = tid >> 6;        // wave = K-quarter
  int q = lane >> 4, ml = lane & 15;
  int tb = tid >> 4, tc = tid & 15;         // act phase: thread owns (batch tb, col tc)

  u16* mbox = h_buf + g * (2 * 16 * 1024);  // group mailbox [2][16][1024]
  u32* gbar = bar + g * 256;

  // stage U slice: LDS row n = gate*16 + colLocal  <-  UT[gate*1024 + wi*16 + colLocal][:]
  for (int cidx = tid; cidx < 8192; cidx += 256) {   // 64 rows * 128 chunks(8 bf16)
    int n = cidx >> 7, kc = cidx & 127;
    int gate = n >> 4, cl = n & 15;
    const u16* src = UT + (long)(gate * 1024 + wi * 16 + cl) * 1024 + kc * 8;
    uint4 v = *(const uint4*)src;
    *(uint4*)&U_lds[n * 1024 + ((kc ^ (n & 7)) << 3)] = v;
  }
  // zero own slice of mailbox parity 0 (coherent store -> visible at LLC)
  __hip_atomic_store(&mbox[tb * 1024 + wi * 16 + tc], (u16)0,
                     __ATOMIC_RELAXED, __HIP_MEMORY_SCOPE_AGENT);
  __syncthreads();                           // drains vmcnt per wave
  if (tid == 0)
    __hip_atomic_fetch_add(&gbar[255], 1u, __ATOMIC_RELAXED, __HIP_MEMORY_SCOPE_AGENT);

  float cstate = 0.f;
  for (int t = 0; t < 128; t++) {
    const u16* hcur = mbox + (t & 1) * 16384;
    u16* hnxt = mbox + ((t + 1) & 1) * 16384;

    // xz prefetch (depends only on t) — in flight during the spin below
    long xb = ((long)(t * 64 + g * 16 + tb)) * 4096 + wi * 16 + tc;
    float xzi = xz[xb], xzf = xz[xb + 1024], xzg = xz[xb + 2048], xzo = xz[xb + 3072];

    // wait until all 64 WGs of this group published h_{t-1}
    if (tid == 0) {
      int slot = (t == 0) ? 255 : (t - 1);
      while (__hip_atomic_load(&gbar[slot], __ATOMIC_RELAXED,
                               __HIP_MEMORY_SCOPE_AGENT) < 64u) {}
    }
    __syncthreads();

    // MFMA: wave w covers k in [w*256, w*256+256); acc_nt = gate nt, cols ml
    f32x4 acc0 = {}, acc1 = {}, acc2 = {}, acc3 = {};
    #pragma unroll
    for (int ki = 0; ki < 8; ki++) {
      int koff = w * 256 + ki * 32 + q * 8;
      const u64* ap = (const u64*)&hcur[ml * 1024 + koff];
      u64 a0 = __hip_atomic_load(ap,     __ATOMIC_RELAXED, __HIP_MEMORY_SCOPE_AGENT);
      u64 a1 = __hip_atomic_load(ap + 1, __ATOMIC_RELAXED, __HIP_MEMORY_SCOPE_AGENT);
      union { u64 u[2]; bf16x8 v; } au; au.u[0] = a0; au.u[1] = a1;
      int sw = ((w * 32 + ki * 4 + q) ^ (ml & 7)) << 3;
      bf16x8 b0 = *(const bf16x8*)&U_lds[(0  + ml) * 1024 + sw];
      bf16x8 b1 = *(const bf16x8*)&U_lds[(16 + ml) * 1024 + sw];
      bf16x8 b2 = *(const bf16x8*)&U_lds[(32 + ml) * 1024 + sw];
      bf16x8 b3 = *(const bf16x8*)&U_lds[(48 + ml) * 1024 + sw];
      acc0 = __builtin_amdgcn_mfma_f32_16x16x32_bf16(au.v, b0, acc0, 0, 0, 0);
      acc1 = __builtin_amdgcn_mfma_f32_16x16x32_bf16(au.v, b1, acc1, 0, 0, 0);
      acc2 = __builtin_amdgcn_mfma_f32_16x16x32_bf16(au.v, b2, acc2, 0, 0, 0);
      acc3 = __builtin_amdgcn_mfma_f32_16x16x32_bf16(au.v, b3, acc3, 0, 0, 0);
    }
    // publish partials: zpart[w][b=q*4+r][gate*16 + ml]
    #pragma unroll
    for (int r = 0; r < 4; r++) {
      float* zp = zpart + w * 1088 + (q * 4 + r) * 68 + ml;
      zp[0]  = acc0[r];
      zp[16] = acc1[r];
      zp[32] = acc2[r];
      zp[48] = acc3[r];
    }
    __syncthreads();

    // activation: thread (tb, tc) sums 4 K-quarters per gate
    float zi = xzi, zf = xzf, zg = xzg, zo = xzo;
    #pragma unroll
    for (int ww = 0; ww < 4; ww++) {
      const float* zp = zpart + ww * 1088 + tb * 68;
      zi += zp[tc]; zf += zp[tc + 16]; zg += zp[tc + 32]; zo += zp[tc + 48];
    }
    float iv = 1.f / (1.f + __expf(-zi));
    float fv = 1.f / (1.f + __expf(-zf));
    float gv = tanhf(zg);
    float ov = 1.f / (1.f + __expf(-zo));
    cstate = fv * cstate + iv * gv;
    float hv = ov * tanhf(cstate);
    u16 hb = f2bf(hv);
    __hip_atomic_store(&hnxt[tb * 1024 + wi * 16 + tc], hb,
                       __ATOMIC_RELAXED, __HIP_MEMORY_SCOPE_AGENT);
    out_seq[((long)(t * 64 + g * 16 + tb)) * 1024 + wi * 16 + tc] = hb;
    if (t == 127) {
      hT[(g * 16 + tb) * 1024 + wi * 16 + tc] = hv;
      cT[(g * 16 + tb) * 1024 + wi * 16 + tc] = cstate;
    }
    __syncthreads();               // all waves drain vmcnt (h stores at LLC)
    if (tid == 0 && t < 127)       // publish h_t; no fence needed (stores coherent)
      __hip_atomic_fetch_add(&gbar[t], 1u, __ATOMIC_RELAXED, __HIP_MEMORY_SCOPE_AGENT);
  }
}

extern "C" void kernel_launch(void* const* d_in, const int* in_sizes, int n_in,
                              void* d_out, int out_size, void* d_ws, size_t ws_size,
                              hipStream_t stream) {
  const int*   inputs = (const int*)d_in[0];
  const float* emb    = (const float*)d_in[1];
  const float* W1     = (const float*)d_in[2];
  const float* U1     = (const float*)d_in[3];
  const float* b1     = (const float*)d_in[4];
  const float* W2     = (const float*)d_in[5];
  const float* U2     = (const float*)d_in[6];
  const float* b2     = (const float*)d_in[7];
  const float* Wout   = (const float*)d_in[8];
  const float* bout   = (const float*)d_in[9];
  float* out = (float*)d_out;
  char* ws = (char*)d_ws;

  size_t off = 0;
  float* xz  = (float*)(ws + off); off += (size_t)8192 * 4096 * 4;   // 134 MB, reused by both layers
  u16* xbf   = (u16*)(ws + off);   off += (size_t)8192 * 1024 * 2;   // x, later reused as out2
  u16* out1  = (u16*)(ws + off);   off += (size_t)8192 * 1024 * 2;
  u16* WT    = (u16*)(ws + off);   off += (size_t)4096 * 1024 * 2;
  u16* UT    = (u16*)(ws + off);   off += (size_t)4096 * 1024 * 2;
  u16* WoT   = (u16*)(ws + off);   off += (size_t)32000 * 1024 * 2;
  u16* hbuf  = (u16*)(ws + off);   off += (size_t)2 * 64 * 1024 * 2;
  u32* bar   = (u32*)(ws + off);   off += 8192;                      // 2 layers x 1024 slots

  float* hT1 = out + (size_t)262144000;
  float* cT1 = hT1 + 65536;
  float* hT2 = cT1 + 65536;
  float* cT2 = hT2 + 65536;

  const int SCAN_LDS = 131072 + 17408;   // U slice + zpart = 148480 B (<= 160 KB/CU)
  hipFuncSetAttribute((const void*)lstm_scan,
                      hipFuncAttributeMaxDynamicSharedMemorySize, SCAN_LDS);

  hipMemsetAsync(bar, 0, 8192, stream);
  embed_kernel<<<8192, 256, 0, stream>>>(inputs, emb, xbf);

  // ---- layer 1
  castT_kernel<<<dim3(128, 32), 256, 0, stream>>>(W1, WT, 4096);
  gemm_bt<<<dim3(32, 64), 256, 0, stream>>>(xbf, WT, b1, xz, 4096, 0);
  castT_kernel<<<dim3(128, 32), 256, 0, stream>>>(U1, UT, 4096);
  {
    const float* p_xz = xz; const u16* p_ut = UT; u16* p_os = out1; u16* p_hb = hbuf;
    float* p_hT = hT1; float* p_cT = cT1; u32* p_bar = bar;
    void* args[] = {&p_xz, &p_ut, &p_os, &p_hb, &p_hT, &p_cT, &p_bar};
    hipLaunchCooperativeKernel((void*)lstm_scan, dim3(256), dim3(256), args, SCAN_LDS, stream);
  }

  // ---- layer 2
  castT_kernel<<<dim3(128, 32), 256, 0, stream>>>(W2, WT, 4096);
  gemm_bt<<<dim3(32, 64), 256, 0, stream>>>(out1, WT, b2, xz, 4096, 0);
  castT_kernel<<<dim3(128, 32), 256, 0, stream>>>(U2, UT, 4096);
  {
    const float* p_xz = xz; const u16* p_ut = UT; u16* p_os = xbf; u16* p_hb = hbuf;
    float* p_hT = hT2; float* p_cT = cT2; u32* p_bar = bar + 1024;
    void* args[] = {&p_xz, &p_ut, &p_os, &p_hb, &p_hT, &p_cT, &p_bar};
    hipLaunchCooperativeKernel((void*)lstm_scan, dim3(256), dim3(256), args, SCAN_LDS, stream);
  }

  // ---- logits
  castT_kernel<<<dim3(1000, 32), 256, 0, stream>>>(Wout, WoT, 32000);
  gemm_bt<<<dim3(250, 64), 256, 0, stream>>>(xbf, WoT, bout, out, 32000, 1);
}